// Round 5
// baseline (170.598 us; speedup 1.0000x reference)
//
#include <hip/hip_runtime.h>
#include <math.h>

// HyperConnection: N=100000, S=4, D=256.
// TWO n per wave (straight-line, no loop), 4 waves/block -> 8 n per block.
// No LDS, no barriers. DPP for intra-16 exchanges; shuffles for xor16/32.
static constexpr int DD = 256;

static constexpr int QXOR1 = 0xB1;  // quad_perm(1,0,3,2)  lane^1
static constexpr int QXOR2 = 0x4E;  // quad_perm(2,3,0,1)  lane^2
static constexpr int ROR4  = 0x124; // row_ror:4
static constexpr int ROR8  = 0x128; // row_ror:8

template <int CTRL>
__device__ __forceinline__ float dpp_add(float v) {
    int p = __builtin_amdgcn_update_dpp(0, __float_as_int(v), CTRL, 0xF, 0xF, true);
    return v + __int_as_float(p);
}
__device__ __forceinline__ float tanh_fast(float x) {
    float e = __expf(2.0f * x);
    return 1.0f - 2.0f * __builtin_amdgcn_rcpf(e + 1.0f);
}
__device__ __forceinline__ float dot4(float4 a, float4 b) {
    return a.x * b.x + a.y * b.y + a.z * b.z + a.w * b.w;
}
__device__ __forceinline__ float rl(float v, int l) {
    return __int_as_float(__builtin_amdgcn_readlane(__float_as_int(v), l));
}

// reduce-scatter 4 sums over 64 lanes; returns 0.25*rsq of each (broadcast)
__device__ __forceinline__ void reduce4_invnorm(
    float ss0, float ss1, float ss2, float ss3, bool hi32, bool hi16,
    float& in0, float& in1, float& in2, float& in3)
{
    float sA = hi32 ? ss0 : ss2;
    float sB = hi32 ? ss1 : ss3;
    float gA = __shfl_xor(sA, 32, 64);
    float gB = __shfl_xor(sB, 32, 64);
    float A0 = (hi32 ? ss2 : ss0) + gA;
    float A1 = (hi32 ? ss3 : ss1) + gB;
    float s2 = hi16 ? A0 : A1;
    float g2 = __shfl_xor(s2, 16, 64);
    float B = (hi16 ? A1 : A0) + g2;
    B = dpp_add<QXOR1>(B);
    B = dpp_add<QXOR2>(B);
    B = dpp_add<ROR4>(B);
    B = dpp_add<ROR8>(B);
    float inv = 0.25f * __builtin_amdgcn_rsqf(fmaxf(B, 1e-24f));
    in0 = rl(inv, 0); in1 = rl(inv, 16); in2 = rl(inv, 32); in3 = rl(inv, 48);
}

// reduce-scatter 6 sums; apply tanh before broadcast
__device__ __forceinline__ void reduce6_tanh(
    float d0, float d1, float d2, float d3, float d4, float d5,
    bool hi32, bool hi16,
    float& td0, float& td1, float& td2, float& td3, float& td4, float& td5)
{
    float sA = hi32 ? d0 : d3;
    float sB = hi32 ? d1 : d4;
    float sC = hi32 ? d2 : d5;
    float gA = __shfl_xor(sA, 32, 64);
    float gB = __shfl_xor(sB, 32, 64);
    float gC = __shfl_xor(sC, 32, 64);
    float A0 = (hi32 ? d3 : d0) + gA;
    float A1 = (hi32 ? d4 : d1) + gB;
    float A2 = (hi32 ? d5 : d2) + gC;
    float e1s = hi16 ? A0 : A2;
    float e1g = __shfl_xor(e1s, 16, 64);
    float e2g = __shfl_xor(A1, 16, 64);
    float R0 = hi16 ? (A2 + e1g) : (A0 + e1g);  // g0:d0 g1:d2 g2:d3 g3:d5
    float R1 = A1 + e2g;                        // g0:d1       g2:d4
    R0 = dpp_add<QXOR1>(R0); R1 = dpp_add<QXOR1>(R1);
    R0 = dpp_add<QXOR2>(R0); R1 = dpp_add<QXOR2>(R1);
    R0 = dpp_add<ROR4>(R0);  R1 = dpp_add<ROR4>(R1);
    R0 = dpp_add<ROR8>(R0);  R1 = dpp_add<ROR8>(R1);
    float T0 = tanh_fast(R0);
    float T1 = tanh_fast(R1);
    td0 = rl(T0, 0);  td1 = rl(T1, 0);
    td2 = rl(T0, 16);
    td3 = rl(T0, 32); td4 = rl(T1, 32);
    td5 = rl(T0, 48);
}

__global__ __launch_bounds__(256) void hyperconn_kernel(
    const float* __restrict__ x_streams,       // (N,4,256)
    const float* __restrict__ message_output,  // (N,256)
    const float* __restrict__ theta_pre,       // (1,256)
    const float* __restrict__ b_pre,           // (1,4)
    const float* __restrict__ theta_post,      // (1,256)
    const float* __restrict__ b_post,          // (1,4)
    const float* __restrict__ Theta_res,       // (4,256)
    const float* __restrict__ B_res,           // (4,4)
    const float* __restrict__ alpha_pre_p,
    const float* __restrict__ alpha_post_p,
    const float* __restrict__ alpha_res_p,
    float* __restrict__ out_x,                 // (N,4,256)
    float* __restrict__ out_hpre,              // (N,4)
    int Ntot)
{
    const int lane = threadIdx.x & 63;
    const int n0 = blockIdx.x * 8 + (threadIdx.x >> 6) * 2;  // this wave: n0, n0+1
    if (n0 >= Ntot) return;
    const bool hasB = (n0 + 1) < Ntot;

    // ---- issue all 10 big loads up front (MLP) ----
    const float4* xp = reinterpret_cast<const float4*>(x_streams) + (size_t)n0 * 256 + lane;
    const float4 ax0 = xp[0 * 64];
    const float4 ax1 = xp[1 * 64];
    const float4 ax2 = xp[2 * 64];
    const float4 ax3 = xp[3 * 64];
    float4 bx0, bx1, bx2, bx3, bmv;
    if (hasB) {
        bx0 = xp[4 * 64];
        bx1 = xp[5 * 64];
        bx2 = xp[6 * 64];
        bx3 = xp[7 * 64];
    }
    const float4* mp = reinterpret_cast<const float4*>(message_output) + (size_t)n0 * 64 + lane;
    const float4 amv = mp[0];
    if (hasB) bmv = mp[64];

    // ---- weights (L1-hot) ----
    const float4 tp = reinterpret_cast<const float4*>(theta_pre)[lane];
    const float4 tq = reinterpret_cast<const float4*>(theta_post)[lane];
    const float4 r0 = reinterpret_cast<const float4*>(Theta_res + 0 * DD)[lane];
    const float4 r1 = reinterpret_cast<const float4*>(Theta_res + 1 * DD)[lane];
    const float4 r2 = reinterpret_cast<const float4*>(Theta_res + 2 * DD)[lane];
    const float4 r3 = reinterpret_cast<const float4*>(Theta_res + 3 * DD)[lane];
    const float Bres_l = B_res[lane & 15];
    const float bpre_l = b_pre[lane & 3];
    const float apre = alpha_pre_p[0], apost = alpha_post_p[0], ares = alpha_res_p[0];
    const float bp0 = b_post[0], bp1 = b_post[1], bp2 = b_post[2], bp3 = b_post[3];

    const bool hi32 = (lane & 32) != 0;
    const bool hi16 = (lane & 16) != 0;
    const int r_id = (lane >> 2) & 3;

    // ---- norms (both n, chains interleave) ----
    float ain0, ain1, ain2, ain3, bin0, bin1, bin2, bin3;
    reduce4_invnorm(dot4(ax0, ax0), dot4(ax1, ax1), dot4(ax2, ax2), dot4(ax3, ax3),
                    hi32, hi16, ain0, ain1, ain2, ain3);
    if (hasB)
        reduce4_invnorm(dot4(bx0, bx0), dot4(bx1, bx1), dot4(bx2, bx2), dot4(bx3, bx3),
                        hi32, hi16, bin0, bin1, bin2, bin3);

    // ---- pooled vectors + 6 dots each ----
    float4 pa, pb;
    pa.x = ain0 * ax0.x + ain1 * ax1.x + ain2 * ax2.x + ain3 * ax3.x;
    pa.y = ain0 * ax0.y + ain1 * ax1.y + ain2 * ax2.y + ain3 * ax3.y;
    pa.z = ain0 * ax0.z + ain1 * ax1.z + ain2 * ax2.z + ain3 * ax3.z;
    pa.w = ain0 * ax0.w + ain1 * ax1.w + ain2 * ax2.w + ain3 * ax3.w;
    float atd0, atd1, atd2, atd3, atd4, atd5;
    float btd0, btd1, btd2, btd3, btd4, btd5;
    reduce6_tanh(dot4(pa, tp), dot4(pa, tq), dot4(pa, r0), dot4(pa, r1), dot4(pa, r2), dot4(pa, r3),
                 hi32, hi16, atd0, atd1, atd2, atd3, atd4, atd5);
    if (hasB) {
        pb.x = bin0 * bx0.x + bin1 * bx1.x + bin2 * bx2.x + bin3 * bx3.x;
        pb.y = bin0 * bx0.y + bin1 * bx1.y + bin2 * bx2.y + bin3 * bx3.y;
        pb.z = bin0 * bx0.z + bin1 * bx1.z + bin2 * bx2.z + bin3 * bx3.z;
        pb.w = bin0 * bx0.w + bin1 * bx1.w + bin2 * bx2.w + bin3 * bx3.w;
        reduce6_tanh(dot4(pb, tp), dot4(pb, tq), dot4(pb, r0), dot4(pb, r1), dot4(pb, r2), dot4(pb, r3),
                     hi32, hi16, btd0, btd1, btd2, btd3, btd4, btd5);
    }

    // ---- two Sinkhorns, explicitly interleaved (ILP-2 on the chain) ----
    float dselA = (r_id < 2) ? (r_id == 0 ? atd2 : atd3) : (r_id == 2 ? atd4 : atd5);
    float MvA = __expf(fmaf(ares, dselA, Bres_l) * 10.0f);
    float MvB = 0.0f;
    if (hasB) {
        float dselB = (r_id < 2) ? (r_id == 0 ? btd2 : btd3) : (r_id == 2 ? btd4 : btd5);
        MvB = __expf(fmaf(ares, dselB, Bres_l) * 10.0f);
    }
#pragma unroll
    for (int it = 0; it < 10; ++it) {
        float rsA = dpp_add<QXOR2>(dpp_add<QXOR1>(MvA));
        float rsB = dpp_add<QXOR2>(dpp_add<QXOR1>(MvB));
        MvA *= __builtin_amdgcn_rcpf(rsA);
        MvB *= __builtin_amdgcn_rcpf(rsB);
        float csA = dpp_add<ROR8>(dpp_add<ROR4>(MvA));
        float csB = dpp_add<ROR8>(dpp_add<ROR4>(MvB));
        MvA *= __builtin_amdgcn_rcpf(csA);
        MvB *= __builtin_amdgcn_rcpf(csB);
    }

    // ---- combined H_pre store: lanes 0-7 cover both n (contiguous 32B) ----
    {
        float td = (lane < 4) ? atd0 : btd0;
        int cnt = hasB ? 8 : 4;
        if (lane < cnt) out_hpre[(size_t)n0 * 4 + lane] = fmaf(apre, td, bpre_l);
    }

    // ---- epilogue n0 ----
    float4* op = reinterpret_cast<float4*>(out_x) + (size_t)n0 * 256 + lane;
    {
        const float m00 = rl(MvA, 0),  m01 = rl(MvA, 1),  m02 = rl(MvA, 2),  m03 = rl(MvA, 3);
        const float m10 = rl(MvA, 4),  m11 = rl(MvA, 5),  m12 = rl(MvA, 6),  m13 = rl(MvA, 7);
        const float m20 = rl(MvA, 8),  m21 = rl(MvA, 9),  m22 = rl(MvA, 10), m23 = rl(MvA, 11);
        const float m30 = rl(MvA, 12), m31 = rl(MvA, 13), m32 = rl(MvA, 14), m33 = rl(MvA, 15);
        const float hpv = fmaf(apost, atd1, 0.0f);
        const float hp0 = hpv + bp0, hp1 = hpv + bp1, hp2 = hpv + bp2, hp3 = hpv + bp3;
        float4 o;
        o.x = m00 * ax0.x + m01 * ax1.x + m02 * ax2.x + m03 * ax3.x + hp0 * amv.x;
        o.y = m00 * ax0.y + m01 * ax1.y + m02 * ax2.y + m03 * ax3.y + hp0 * amv.y;
        o.z = m00 * ax0.z + m01 * ax1.z + m02 * ax2.z + m03 * ax3.z + hp0 * amv.z;
        o.w = m00 * ax0.w + m01 * ax1.w + m02 * ax2.w + m03 * ax3.w + hp0 * amv.w;
        op[0 * 64] = o;
        o.x = m10 * ax0.x + m11 * ax1.x + m12 * ax2.x + m13 * ax3.x + hp1 * amv.x;
        o.y = m10 * ax0.y + m11 * ax1.y + m12 * ax2.y + m13 * ax3.y + hp1 * amv.y;
        o.z = m10 * ax0.z + m11 * ax1.z + m12 * ax2.z + m13 * ax3.z + hp1 * amv.z;
        o.w = m10 * ax0.w + m11 * ax1.w + m12 * ax2.w + m13 * ax3.w + hp1 * amv.w;
        op[1 * 64] = o;
        o.x = m20 * ax0.x + m21 * ax1.x + m22 * ax2.x + m23 * ax3.x + hp2 * amv.x;
        o.y = m20 * ax0.y + m21 * ax1.y + m22 * ax2.y + m23 * ax3.y + hp2 * amv.y;
        o.z = m20 * ax0.z + m21 * ax1.z + m22 * ax2.z + m23 * ax3.z + hp2 * amv.z;
        o.w = m20 * ax0.w + m21 * ax1.w + m22 * ax2.w + m23 * ax3.w + hp2 * amv.w;
        op[2 * 64] = o;
        o.x = m30 * ax0.x + m31 * ax1.x + m32 * ax2.x + m33 * ax3.x + hp3 * amv.x;
        o.y = m30 * ax0.y + m31 * ax1.y + m32 * ax2.y + m33 * ax3.y + hp3 * amv.y;
        o.z = m30 * ax0.z + m31 * ax1.z + m32 * ax2.z + m33 * ax3.z + hp3 * amv.z;
        o.w = m30 * ax0.w + m31 * ax1.w + m32 * ax2.w + m33 * ax3.w + hp3 * amv.w;
        op[3 * 64] = o;
    }

    // ---- epilogue n1 ----
    if (hasB) {
        const float m00 = rl(MvB, 0),  m01 = rl(MvB, 1),  m02 = rl(MvB, 2),  m03 = rl(MvB, 3);
        const float m10 = rl(MvB, 4),  m11 = rl(MvB, 5),  m12 = rl(MvB, 6),  m13 = rl(MvB, 7);
        const float m20 = rl(MvB, 8),  m21 = rl(MvB, 9),  m22 = rl(MvB, 10), m23 = rl(MvB, 11);
        const float m30 = rl(MvB, 12), m31 = rl(MvB, 13), m32 = rl(MvB, 14), m33 = rl(MvB, 15);
        const float hpv = fmaf(apost, btd1, 0.0f);
        const float hp0 = hpv + bp0, hp1 = hpv + bp1, hp2 = hpv + bp2, hp3 = hpv + bp3;
        float4 o;
        o.x = m00 * bx0.x + m01 * bx1.x + m02 * bx2.x + m03 * bx3.x + hp0 * bmv.x;
        o.y = m00 * bx0.y + m01 * bx1.y + m02 * bx2.y + m03 * bx3.y + hp0 * bmv.y;
        o.z = m00 * bx0.z + m01 * bx1.z + m02 * bx2.z + m03 * bx3.z + hp0 * bmv.z;
        o.w = m00 * bx0.w + m01 * bx1.w + m02 * bx2.w + m03 * bx3.w + hp0 * bmv.w;
        op[4 * 64] = o;
        o.x = m10 * bx0.x + m11 * bx1.x + m12 * bx2.x + m13 * bx3.x + hp1 * bmv.x;
        o.y = m10 * bx0.y + m11 * bx1.y + m12 * bx2.y + m13 * bx3.y + hp1 * bmv.y;
        o.z = m10 * bx0.z + m11 * bx1.z + m12 * bx2.z + m13 * bx3.z + hp1 * bmv.z;
        o.w = m10 * bx0.w + m11 * bx1.w + m12 * bx2.w + m13 * bx3.w + hp1 * bmv.w;
        op[5 * 64] = o;
        o.x = m20 * bx0.x + m21 * bx1.x + m22 * bx2.x + m23 * bx3.x + hp2 * bmv.x;
        o.y = m20 * bx0.y + m21 * bx1.y + m22 * bx2.y + m23 * bx3.y + hp2 * bmv.y;
        o.z = m20 * bx0.z + m21 * bx1.z + m22 * bx2.z + m23 * bx3.z + hp2 * bmv.z;
        o.w = m20 * bx0.w + m21 * bx1.w + m22 * bx2.w + m23 * bx3.w + hp2 * bmv.w;
        op[6 * 64] = o;
        o.x = m30 * bx0.x + m31 * bx1.x + m32 * bx2.x + m33 * bx3.x + hp3 * bmv.x;
        o.y = m30 * bx0.y + m31 * bx1.y + m32 * bx2.y + m33 * bx3.y + hp3 * bmv.y;
        o.z = m30 * bx0.z + m31 * bx1.z + m32 * bx2.z + m33 * bx3.z + hp3 * bmv.z;
        o.w = m30 * bx0.w + m31 * bx1.w + m32 * bx2.w + m33 * bx3.w + hp3 * bmv.w;
        op[7 * 64] = o;
    }
}

extern "C" void kernel_launch(void* const* d_in, const int* in_sizes, int n_in,
                              void* d_out, int out_size, void* d_ws, size_t ws_size,
                              hipStream_t stream) {
    const float* x_streams      = (const float*)d_in[0];
    const float* message_output = (const float*)d_in[1];
    const float* theta_pre      = (const float*)d_in[2];
    const float* b_pre          = (const float*)d_in[3];
    const float* theta_post     = (const float*)d_in[4];
    const float* b_post         = (const float*)d_in[5];
    const float* Theta_res      = (const float*)d_in[6];
    const float* B_res          = (const float*)d_in[7];
    const float* alpha_pre      = (const float*)d_in[8];
    const float* alpha_post     = (const float*)d_in[9];
    const float* alpha_res      = (const float*)d_in[10];

    const int N = in_sizes[0] / (4 * DD);
    float* out_x = (float*)d_out;
    float* out_hpre = out_x + (size_t)N * 4 * DD;

    const int nblocks = (N + 7) / 8;  // 2 n per wave, 4 waves per block
    hyperconn_kernel<<<nblocks, 256, 0, stream>>>(
        x_streams, message_output, theta_pre, b_pre, theta_post, b_post,
        Theta_res, B_res, alpha_pre, alpha_post, alpha_res, out_x, out_hpre, N);
}

// Round 7
// 156.898 us; speedup vs baseline: 1.0873x; 1.0873x over previous
//
#include <hip/hip_runtime.h>
#include <math.h>

// HyperConnection: N=100000, S=4, D=256.
// One wave per n, 4 waves/block, fully wave-independent: no LDS, no barriers.
// DPP for intra-16 exchanges; shuffles only for xor16/xor32 reduce steps.
// Round 7: non-temporal stores for out_x/out_hpre via native ext_vector_type
// (avoid L2/L3 write pollution so x keeps partial L3 residency across replays).
static constexpr int DD = 256;

typedef float floatx4 __attribute__((ext_vector_type(4)));

// DPP control codes
static constexpr int QXOR1 = 0xB1;  // quad_perm(1,0,3,2)  lane^1
static constexpr int QXOR2 = 0x4E;  // quad_perm(2,3,0,1)  lane^2
static constexpr int ROR4  = 0x124; // row_ror:4
static constexpr int ROR8  = 0x128; // row_ror:8

template <int CTRL>
__device__ __forceinline__ float dpp_add(float v) {
    int p = __builtin_amdgcn_update_dpp(0, __float_as_int(v), CTRL, 0xF, 0xF, true);
    return v + __int_as_float(p);
}
__device__ __forceinline__ float tanh_fast(float x) {
    float e = __expf(2.0f * x);
    return 1.0f - 2.0f * __builtin_amdgcn_rcpf(e + 1.0f);
}
__device__ __forceinline__ float dot4(float4 a, float4 b) {
    return a.x * b.x + a.y * b.y + a.z * b.z + a.w * b.w;
}
__device__ __forceinline__ float rl(float v, int l) {
    return __int_as_float(__builtin_amdgcn_readlane(__float_as_int(v), l));
}
__device__ __forceinline__ void nt_store4(float4* p, float4 v) {
    floatx4 nv;
    nv.x = v.x; nv.y = v.y; nv.z = v.z; nv.w = v.w;
    __builtin_nontemporal_store(nv, reinterpret_cast<floatx4*>(p));
}

__global__ __launch_bounds__(256) void hyperconn_kernel(
    const float* __restrict__ x_streams,       // (N,4,256)
    const float* __restrict__ message_output,  // (N,256)
    const float* __restrict__ theta_pre,       // (1,256)
    const float* __restrict__ b_pre,           // (1,4)
    const float* __restrict__ theta_post,      // (1,256)
    const float* __restrict__ b_post,          // (1,4)
    const float* __restrict__ Theta_res,       // (4,256)
    const float* __restrict__ B_res,           // (4,4)
    const float* __restrict__ alpha_pre_p,
    const float* __restrict__ alpha_post_p,
    const float* __restrict__ alpha_res_p,
    float* __restrict__ out_x,                 // (N,4,256)
    float* __restrict__ out_hpre,              // (N,4)
    int Ntot)
{
    const int lane = threadIdx.x & 63;
    const int n = blockIdx.x * 4 + (threadIdx.x >> 6);
    if (n >= Ntot) return;  // wave-uniform exit

    // ---- x rows + msg: one base, 4 loads with immediate offsets ----
    const float4* xp = reinterpret_cast<const float4*>(x_streams) + (size_t)n * 64 * 4 + lane;
    const float4 cx0 = xp[0 * 64];
    const float4 cx1 = xp[1 * 64];
    const float4 cx2 = xp[2 * 64];
    const float4 cx3 = xp[3 * 64];
    const float4 cmv = reinterpret_cast<const float4*>(message_output)[(size_t)n * 64 + lane];

    // ---- weights (L1/L2-hot) ----
    const float4 tp = reinterpret_cast<const float4*>(theta_pre)[lane];
    const float4 tq = reinterpret_cast<const float4*>(theta_post)[lane];
    const float4 r0 = reinterpret_cast<const float4*>(Theta_res + 0 * DD)[lane];
    const float4 r1 = reinterpret_cast<const float4*>(Theta_res + 1 * DD)[lane];
    const float4 r2 = reinterpret_cast<const float4*>(Theta_res + 2 * DD)[lane];
    const float4 r3 = reinterpret_cast<const float4*>(Theta_res + 3 * DD)[lane];
    const float Bres_l = B_res[lane & 15];
    const float bpre_l = b_pre[lane & 3];
    const float apre = alpha_pre_p[0], apost = alpha_post_p[0], ares = alpha_res_p[0];
    const float bp0 = b_post[0], bp1 = b_post[1], bp2 = b_post[2], bp3 = b_post[3];

    const bool hi32 = (lane & 32) != 0;
    const bool hi16 = (lane & 16) != 0;
    const int r_id = (lane >> 2) & 3;

    // ---- per-row sumsq partials ----
    float ss0 = dot4(cx0, cx0), ss1 = dot4(cx1, cx1);
    float ss2 = dot4(cx2, cx2), ss3 = dot4(cx3, cx3);

    // reduce-scatter 4 values: xor32 (2 shfl), xor16 (1 shfl), DPP-sum within 16.
    float in0, in1, in2, in3;
    {
        float sA = hi32 ? ss0 : ss2;
        float sB = hi32 ? ss1 : ss3;
        float gA = __shfl_xor(sA, 32, 64);
        float gB = __shfl_xor(sB, 32, 64);
        float A0 = (hi32 ? ss2 : ss0) + gA;  // lo32:{ss0,ss1} hi32:{ss2,ss3}
        float A1 = (hi32 ? ss3 : ss1) + gB;
        float s2 = hi16 ? A0 : A1;
        float g2 = __shfl_xor(s2, 16, 64);
        float B = (hi16 ? A1 : A0) + g2;     // group g owns ss_g
        B = dpp_add<QXOR1>(B);
        B = dpp_add<QXOR2>(B);
        B = dpp_add<ROR4>(B);
        B = dpp_add<ROR8>(B);
        // rsq BEFORE broadcast: 1 issue instead of 4
        float inv = 0.25f * __builtin_amdgcn_rsqf(fmaxf(B, 1e-24f));
        in0 = rl(inv, 0); in1 = rl(inv, 16); in2 = rl(inv, 32); in3 = rl(inv, 48);
    }

    // ---- pooled vector, 6 weight dots ----
    float4 p;
    p.x = in0 * cx0.x + in1 * cx1.x + in2 * cx2.x + in3 * cx3.x;
    p.y = in0 * cx0.y + in1 * cx1.y + in2 * cx2.y + in3 * cx3.y;
    p.z = in0 * cx0.z + in1 * cx1.z + in2 * cx2.z + in3 * cx3.z;
    p.w = in0 * cx0.w + in1 * cx1.w + in2 * cx2.w + in3 * cx3.w;

    float d0 = dot4(p, tp), d1 = dot4(p, tq);
    float d2 = dot4(p, r0), d3 = dot4(p, r1), d4 = dot4(p, r2), d5 = dot4(p, r3);

    // reduce-scatter 6 values; tanh BEFORE broadcast (2 issues instead of 6)
    float td0, td1, td2, td3, td4, td5;
    {
        float sA = hi32 ? d0 : d3;
        float sB = hi32 ? d1 : d4;
        float sC = hi32 ? d2 : d5;
        float gA = __shfl_xor(sA, 32, 64);
        float gB = __shfl_xor(sB, 32, 64);
        float gC = __shfl_xor(sC, 32, 64);
        float A0 = (hi32 ? d3 : d0) + gA;  // lo32:{d0,d1,d2} hi32:{d3,d4,d5}
        float A1 = (hi32 ? d4 : d1) + gB;
        float A2 = (hi32 ? d5 : d2) + gC;
        float e1s = hi16 ? A0 : A2;
        float e1g = __shfl_xor(e1s, 16, 64);
        float e2g = __shfl_xor(A1, 16, 64);
        float R0 = hi16 ? (A2 + e1g) : (A0 + e1g);  // g0:d0 g1:d2 g2:d3 g3:d5
        float R1 = A1 + e2g;                        // g0:d1       g2:d4
        R0 = dpp_add<QXOR1>(R0); R1 = dpp_add<QXOR1>(R1);
        R0 = dpp_add<QXOR2>(R0); R1 = dpp_add<QXOR2>(R1);
        R0 = dpp_add<ROR4>(R0);  R1 = dpp_add<ROR4>(R1);
        R0 = dpp_add<ROR8>(R0);  R1 = dpp_add<ROR8>(R1);
        float T0 = tanh_fast(R0);
        float T1 = tanh_fast(R1);
        td0 = rl(T0, 0);  td1 = rl(T1, 0);
        td2 = rl(T0, 16);
        td3 = rl(T0, 32); td4 = rl(T1, 32);
        td5 = rl(T0, 48);
    }

    // ---- Sinkhorn: lane e = lane&15 holds M[e>>2][e&3]; all-DPP ----
    float dsel = (r_id < 2) ? (r_id == 0 ? td2 : td3) : (r_id == 2 ? td4 : td5);
    float Mv = __expf(fmaf(ares, dsel, Bres_l) * 10.0f);
#pragma unroll
    for (int it = 0; it < 10; ++it) {
        float rs = dpp_add<QXOR2>(dpp_add<QXOR1>(Mv));  // row sum (over c)
        Mv *= __builtin_amdgcn_rcpf(rs);
        float cs = dpp_add<ROR8>(dpp_add<ROR4>(Mv));    // col sum (over r)
        Mv *= __builtin_amdgcn_rcpf(cs);
    }

    // ---- broadcast coefficients (SGPR-uniform) ----
    const float m00 = rl(Mv, 0),  m01 = rl(Mv, 1),  m02 = rl(Mv, 2),  m03 = rl(Mv, 3);
    const float m10 = rl(Mv, 4),  m11 = rl(Mv, 5),  m12 = rl(Mv, 6),  m13 = rl(Mv, 7);
    const float m20 = rl(Mv, 8),  m21 = rl(Mv, 9),  m22 = rl(Mv, 10), m23 = rl(Mv, 11);
    const float m30 = rl(Mv, 12), m31 = rl(Mv, 13), m32 = rl(Mv, 14), m33 = rl(Mv, 15);
    const float hp0 = fmaf(apost, td1, bp0), hp1 = fmaf(apost, td1, bp1);
    const float hp2 = fmaf(apost, td1, bp2), hp3 = fmaf(apost, td1, bp3);

    if (lane < 4) {
        float hv = fmaf(apre, td0, bpre_l);
        __builtin_nontemporal_store(hv, &out_hpre[(size_t)n * 4 + lane]);
    }

    // ---- epilogue: out[s] = sum_t M[s][t]*x_t + hpost[s]*msg (nt stores) ----
    float4* op = reinterpret_cast<float4*>(out_x) + (size_t)n * 64 * 4 + lane;
    float4 o;
    o.x = m00 * cx0.x + m01 * cx1.x + m02 * cx2.x + m03 * cx3.x + hp0 * cmv.x;
    o.y = m00 * cx0.y + m01 * cx1.y + m02 * cx2.y + m03 * cx3.y + hp0 * cmv.y;
    o.z = m00 * cx0.z + m01 * cx1.z + m02 * cx2.z + m03 * cx3.z + hp0 * cmv.z;
    o.w = m00 * cx0.w + m01 * cx1.w + m02 * cx2.w + m03 * cx3.w + hp0 * cmv.w;
    nt_store4(&op[0 * 64], o);
    o.x = m10 * cx0.x + m11 * cx1.x + m12 * cx2.x + m13 * cx3.x + hp1 * cmv.x;
    o.y = m10 * cx0.y + m11 * cx1.y + m12 * cx2.y + m13 * cx3.y + hp1 * cmv.y;
    o.z = m10 * cx0.z + m11 * cx1.z + m12 * cx2.z + m13 * cx3.z + hp1 * cmv.z;
    o.w = m10 * cx0.w + m11 * cx1.w + m12 * cx2.w + m13 * cx3.w + hp1 * cmv.w;
    nt_store4(&op[1 * 64], o);
    o.x = m20 * cx0.x + m21 * cx1.x + m22 * cx2.x + m23 * cx3.x + hp2 * cmv.x;
    o.y = m20 * cx0.y + m21 * cx1.y + m22 * cx2.y + m23 * cx3.y + hp2 * cmv.y;
    o.z = m20 * cx0.z + m21 * cx1.z + m22 * cx2.z + m23 * cx3.z + hp2 * cmv.z;
    o.w = m20 * cx0.w + m21 * cx1.w + m22 * cx2.w + m23 * cx3.w + hp2 * cmv.w;
    nt_store4(&op[2 * 64], o);
    o.x = m30 * cx0.x + m31 * cx1.x + m32 * cx2.x + m33 * cx3.x + hp3 * cmv.x;
    o.y = m30 * cx0.y + m31 * cx1.y + m32 * cx2.y + m33 * cx3.y + hp3 * cmv.y;
    o.z = m30 * cx0.z + m31 * cx1.z + m32 * cx2.z + m33 * cx3.z + hp3 * cmv.z;
    o.w = m30 * cx0.w + m31 * cx1.w + m32 * cx2.w + m33 * cx3.w + hp3 * cmv.w;
    nt_store4(&op[3 * 64], o);
}

extern "C" void kernel_launch(void* const* d_in, const int* in_sizes, int n_in,
                              void* d_out, int out_size, void* d_ws, size_t ws_size,
                              hipStream_t stream) {
    const float* x_streams      = (const float*)d_in[0];
    const float* message_output = (const float*)d_in[1];
    const float* theta_pre      = (const float*)d_in[2];
    const float* b_pre          = (const float*)d_in[3];
    const float* theta_post     = (const float*)d_in[4];
    const float* b_post         = (const float*)d_in[5];
    const float* Theta_res      = (const float*)d_in[6];
    const float* B_res          = (const float*)d_in[7];
    const float* alpha_pre      = (const float*)d_in[8];
    const float* alpha_post     = (const float*)d_in[9];
    const float* alpha_res      = (const float*)d_in[10];

    const int N = in_sizes[0] / (4 * DD);
    float* out_x = (float*)d_out;
    float* out_hpre = out_x + (size_t)N * 4 * DD;

    const int nblocks = (N + 3) / 4;  // one wave per n
    hyperconn_kernel<<<nblocks, 256, 0, stream>>>(
        x_streams, message_output, theta_pre, b_pre, theta_post, b_post,
        Theta_res, B_res, alpha_pre, alpha_post, alpha_res, out_x, out_hpre, N);
}